// Round 1
// baseline (3580.232 us; speedup 1.0000x reference)
//
#include <hip/hip_runtime.h>
#include <hip/hip_bf16.h>
#include <math.h>

#define DIM   512
#define RANK  4
#define NROW  2048    // BATCH * SEQ
#define HEADS 8
#define DH    64
#define NH    16384   // NROW * HEADS
#define KW    4       // waves per block in attn (key split)
#define TK    64      // key tile
#define EPS   1e-8f

// ---------------------------------------------------------------------------
// Kernel 1: TT projections q,k,v + L2-normalize q,k per head-row.
//   t[r] = sum_d x[d]*B[r][d];  y[o] = b[o] + sum_r t[r]*A[o][r]
// qq/kq/vv laid out as [NH][DH] == row n occupies [n*512 .. n*512+511].
// ---------------------------------------------------------------------------
__global__ __launch_bounds__(256) void proj_qkv(
    const float* __restrict__ x,
    const float* __restrict__ qA, const float* __restrict__ qB, const float* __restrict__ qb,
    const float* __restrict__ kA, const float* __restrict__ kB, const float* __restrict__ kb,
    const float* __restrict__ vA, const float* __restrict__ vB, const float* __restrict__ vb,
    float* __restrict__ qq, float* __restrict__ kq, float* __restrict__ vv)
{
    __shared__ float qrow[DIM], krow[DIM];
    __shared__ float wred[4][12];
    __shared__ float tvals[12];
    __shared__ float norms[16];

    const int n = blockIdx.x, t = threadIdx.x;
    const int wid = t >> 6, lane = t & 63;

    const float x0 = x[n * DIM + t];
    const float x1 = x[n * DIM + t + 256];

    float p[12];
    #pragma unroll
    for (int r = 0; r < 4; ++r) {
        p[r]     = x0 * qB[r * DIM + t] + x1 * qB[r * DIM + t + 256];
        p[4 + r] = x0 * kB[r * DIM + t] + x1 * kB[r * DIM + t + 256];
        p[8 + r] = x0 * vB[r * DIM + t] + x1 * vB[r * DIM + t + 256];
    }
    #pragma unroll
    for (int i = 0; i < 12; ++i) {
        #pragma unroll
        for (int off = 32; off; off >>= 1) p[i] += __shfl_xor(p[i], off);
    }
    if (lane == 0) {
        #pragma unroll
        for (int i = 0; i < 12; ++i) wred[wid][i] = p[i];
    }
    __syncthreads();
    if (t < 12) tvals[t] = wred[0][t] + wred[1][t] + wred[2][t] + wred[3][t];
    __syncthreads();

    float tq[4], tk[4], tv[4];
    #pragma unroll
    for (int r = 0; r < 4; ++r) { tq[r] = tvals[r]; tk[r] = tvals[4 + r]; tv[r] = tvals[8 + r]; }

    #pragma unroll
    for (int h = 0; h < 2; ++h) {
        const int o = t + h * 256;
        float yq = qb[o], yk = kb[o], yv = vb[o];
        #pragma unroll
        for (int r = 0; r < 4; ++r) {
            yq += tq[r] * qA[o * RANK + r];
            yk += tk[r] * kA[o * RANK + r];
            yv += tv[r] * vA[o * RANK + r];
        }
        qrow[o] = yq; krow[o] = yk;
        vv[n * DIM + o] = yv;
    }
    __syncthreads();

    // per-64-chunk L2 norms for q and k (chunk c reduced by 32 threads)
    {
        const int c = t >> 5, i2 = t & 31;
        const float a  = qrow[c * 64 + i2], b2 = qrow[c * 64 + i2 + 32];
        const float ak = krow[c * 64 + i2], bk = krow[c * 64 + i2 + 32];
        float s  = a * a + b2 * b2;
        float sk = ak * ak + bk * bk;
        #pragma unroll
        for (int off = 16; off; off >>= 1) { s += __shfl_xor(s, off); sk += __shfl_xor(sk, off); }
        if (i2 == 0) { norms[c] = sqrtf(s); norms[8 + c] = sqrtf(sk); }
    }
    __syncthreads();

    #pragma unroll
    for (int h = 0; h < 2; ++h) {
        const int o = t + h * 256;
        const int c = o >> 6;
        qq[n * DIM + o] = qrow[o] / (norms[c] + EPS);
        kq[n * DIM + o] = krow[o] / (norms[8 + c] + EPS);
    }
}

// ---------------------------------------------------------------------------
// Kernel 2: flat attention over NH=16384 rows. No max-subtraction needed:
// logits in [-0.125, 0.125]. Each lane owns one query; 4 waves split keys.
// ---------------------------------------------------------------------------
__global__ __launch_bounds__(256) void attn_kernel(
    const float* __restrict__ qq, const float* __restrict__ kq,
    const float* __restrict__ vv, float* __restrict__ att)
{
    __shared__ float K_lds[KW][TK][DH];   // 64 KB
    __shared__ float V_lds[KW][TK][DH];   // 64 KB
    __shared__ float denred[256];

    const int qbase = blockIdx.x * 64;
    const int t = threadIdx.x;
    const int wid = t >> 6, lane = t & 63;
    const int q = qbase + lane;

    // query row -> registers
    float qreg[DH];
    #pragma unroll
    for (int d = 0; d < DH; d += 4) {
        const float4 f = *(const float4*)&qq[(size_t)q * DH + d];
        qreg[d] = f.x; qreg[d + 1] = f.y; qreg[d + 2] = f.z; qreg[d + 3] = f.w;
    }

    float acc[DH];
    #pragma unroll
    for (int d = 0; d < DH; ++d) acc[d] = 0.f;
    float den = 0.f;

    const int keys_per_wave = NH / KW;        // 4096
    const int ntile = keys_per_wave / TK;     // 64

    for (int tile = 0; tile < ntile; ++tile) {
        const int kb = wid * keys_per_wave + tile * TK;
        __syncthreads();   // prev tile's LDS reads done (all waves same trip count)
        // stage K/V tile: 16 reps x 4 rows, coalesced 1KB per instruction
        #pragma unroll
        for (int rep = 0; rep < 16; ++rep) {
            const int j  = rep * 4 + (lane >> 4);
            const int d4 = (lane & 15) * 4;
            *(float4*)&K_lds[wid][j][d4] = *(const float4*)&kq[(size_t)(kb + j) * DH + d4];
            *(float4*)&V_lds[wid][j][d4] = *(const float4*)&vv[(size_t)(kb + j) * DH + d4];
        }
        __syncthreads();

        #pragma unroll 1
        for (int j0 = 0; j0 < TK; j0 += 8) {
            float w[8];
            #pragma unroll
            for (int jj = 0; jj < 8; ++jj) {
                float s = 0.f;
                #pragma unroll
                for (int d = 0; d < DH; d += 4) {
                    const float4 kv = *(const float4*)&K_lds[wid][j0 + jj][d];  // broadcast
                    s += qreg[d] * kv.x + qreg[d + 1] * kv.y + qreg[d + 2] * kv.z + qreg[d + 3] * kv.w;
                }
                w[jj] = __expf(s * 0.125f);
            }
            #pragma unroll
            for (int jj = 0; jj < 8; ++jj) den += w[jj];
            #pragma unroll
            for (int d = 0; d < DH; d += 4) {
                #pragma unroll
                for (int jj = 0; jj < 8; ++jj) {
                    const float4 v4 = *(const float4*)&V_lds[wid][j0 + jj][d];  // broadcast
                    acc[d]     += w[jj] * v4.x;
                    acc[d + 1] += w[jj] * v4.y;
                    acc[d + 2] += w[jj] * v4.z;
                    acc[d + 3] += w[jj] * v4.w;
                }
            }
        }
    }

    // cross-wave combine. red viewed as [DH][256] over K_lds (16384 floats).
    __syncthreads();
    float* red = &K_lds[0][0][0];
    #pragma unroll
    for (int d = 0; d < DH; ++d) red[d * 256 + wid * 64 + lane] = acc[d];
    denred[wid * 64 + lane] = den;
    __syncthreads();

    const int qi = t & 63, dp = t >> 6;
    const float dtot = denred[qi] + denred[64 + qi] + denred[128 + qi] + denred[192 + qi];
    const float inv = 1.f / dtot;
    #pragma unroll
    for (int i = 0; i < 16; ++i) {
        const int d = dp * 16 + i;
        const float s = red[d * 256 + qi] + red[d * 256 + 64 + qi]
                      + red[d * 256 + 128 + qi] + red[d * 256 + 192 + qi];
        att[(size_t)(qbase + qi) * DH + d] = s * inv;
    }
}

// ---------------------------------------------------------------------------
// Kernel 3: measure (per-head squared-amplitude normalize) + TT output proj.
// ---------------------------------------------------------------------------
__global__ __launch_bounds__(256) void out_proj(
    const float* __restrict__ att, const float* __restrict__ oA,
    const float* __restrict__ oB, const float* __restrict__ ob,
    float* __restrict__ out)
{
    __shared__ float csum[8];
    __shared__ float wred[4][4];
    __shared__ float tvals[4];

    const int n = blockIdx.x, t = threadIdx.x;
    const int wid = t >> 6, lane = t & 63;

    const float a0 = att[n * DIM + t];
    const float a1 = att[n * DIM + t + 256];
    float s0 = a0 * a0, s1 = a1 * a1;
    #pragma unroll
    for (int off = 32; off; off >>= 1) { s0 += __shfl_xor(s0, off); s1 += __shfl_xor(s1, off); }
    if (lane == 0) { csum[wid] = s0; csum[4 + wid] = s1; }
    __syncthreads();

    const float m0 = a0 * a0 / (csum[wid] + EPS);
    const float m1 = a1 * a1 / (csum[4 + wid] + EPS);

    float p[4];
    #pragma unroll
    for (int r = 0; r < 4; ++r) p[r] = m0 * oB[r * DIM + t] + m1 * oB[r * DIM + t + 256];
    #pragma unroll
    for (int r = 0; r < 4; ++r) {
        #pragma unroll
        for (int off = 32; off; off >>= 1) p[r] += __shfl_xor(p[r], off);
    }
    if (lane == 0) {
        #pragma unroll
        for (int r = 0; r < 4; ++r) wred[wid][r] = p[r];
    }
    __syncthreads();
    if (t < 4) tvals[t] = wred[0][t] + wred[1][t] + wred[2][t] + wred[3][t];
    __syncthreads();

    #pragma unroll
    for (int h = 0; h < 2; ++h) {
        const int o = t + h * 256;
        float y = ob[o];
        #pragma unroll
        for (int r = 0; r < 4; ++r) y += tvals[r] * oA[o * RANK + r];
        out[n * DIM + o] = y;
    }
}

// ---------------------------------------------------------------------------
extern "C" void kernel_launch(void* const* d_in, const int* in_sizes, int n_in,
                              void* d_out, int out_size, void* d_ws, size_t ws_size,
                              hipStream_t stream) {
    const float* x  = (const float*)d_in[0];
    const float* qA = (const float*)d_in[1];
    const float* qB = (const float*)d_in[2];
    const float* qb = (const float*)d_in[3];
    const float* kA = (const float*)d_in[4];
    const float* kB = (const float*)d_in[5];
    const float* kb = (const float*)d_in[6];
    const float* vA = (const float*)d_in[7];
    const float* vB = (const float*)d_in[8];
    const float* vb = (const float*)d_in[9];
    const float* oA = (const float*)d_in[10];
    const float* oB = (const float*)d_in[11];
    const float* ob = (const float*)d_in[12];

    float* ws  = (float*)d_ws;                 // needs 16 MB
    float* qq  = ws;
    float* kq  = ws + (size_t)NH * DH;
    float* vv  = ws + 2 * (size_t)NH * DH;
    float* att = ws + 3 * (size_t)NH * DH;
    float* out = (float*)d_out;

    proj_qkv<<<NROW, 256, 0, stream>>>(x, qA, qB, qb, kA, kB, kb, vA, vB, vb, qq, kq, vv);
    attn_kernel<<<NH / 64, 256, 0, stream>>>(qq, kq, vv, att);
    out_proj<<<NROW, 256, 0, stream>>>(att, oA, oB, ob, out);
}

// Round 2
// 315.608 us; speedup vs baseline: 11.3439x; 11.3439x over previous
//
#include <hip/hip_runtime.h>
#include <math.h>

#define DIM   512
#define RANK  4
#define NROW  2048    // BATCH * SEQ
#define DH    64
#define NH    16384   // NROW * HEADS
#define EPS   1e-8f

typedef short bf16x8 __attribute__((ext_vector_type(8)));
typedef float f32x4  __attribute__((ext_vector_type(4)));

static __device__ __forceinline__ ushort f2bf(float f) {
    uint u = __float_as_uint(f);
    u += 0x7FFFu + ((u >> 16) & 1u);   // round-to-nearest-even
    return (ushort)(u >> 16);
}

// ---------------------------------------------------------------------------
// Kernel 1: TT projections q,k,v + L2-normalize q,k per head-row.
// Outputs: qq_b/kq_b bf16 [NH][DH] (flat == [n][512]), vvT bf16 [DH][NH].
// ---------------------------------------------------------------------------
__global__ __launch_bounds__(256) void proj_qkv(
    const float* __restrict__ x,
    const float* __restrict__ qA, const float* __restrict__ qB, const float* __restrict__ qb,
    const float* __restrict__ kA, const float* __restrict__ kB, const float* __restrict__ kb,
    const float* __restrict__ vA, const float* __restrict__ vB, const float* __restrict__ vb,
    ushort* __restrict__ qq_b, ushort* __restrict__ kq_b, ushort* __restrict__ vvT)
{
    __shared__ float qrow[DIM], krow[DIM], vrowS[DIM];
    __shared__ float wred[4][12];
    __shared__ float tvals[12];
    __shared__ float norms[16];

    const int n = blockIdx.x, t = threadIdx.x;
    const int wid = t >> 6, lane = t & 63;

    const float x0 = x[n * DIM + t];
    const float x1 = x[n * DIM + t + 256];

    float p[12];
    #pragma unroll
    for (int r = 0; r < 4; ++r) {
        p[r]     = x0 * qB[r * DIM + t] + x1 * qB[r * DIM + t + 256];
        p[4 + r] = x0 * kB[r * DIM + t] + x1 * kB[r * DIM + t + 256];
        p[8 + r] = x0 * vB[r * DIM + t] + x1 * vB[r * DIM + t + 256];
    }
    #pragma unroll
    for (int i = 0; i < 12; ++i) {
        #pragma unroll
        for (int off = 32; off; off >>= 1) p[i] += __shfl_xor(p[i], off);
    }
    if (lane == 0) {
        #pragma unroll
        for (int i = 0; i < 12; ++i) wred[wid][i] = p[i];
    }
    __syncthreads();
    if (t < 12) tvals[t] = wred[0][t] + wred[1][t] + wred[2][t] + wred[3][t];
    __syncthreads();

    float tq[4], tk[4], tv[4];
    #pragma unroll
    for (int r = 0; r < 4; ++r) { tq[r] = tvals[r]; tk[r] = tvals[4 + r]; tv[r] = tvals[8 + r]; }

    #pragma unroll
    for (int h = 0; h < 2; ++h) {
        const int o = t + h * 256;
        float yq = qb[o], yk = kb[o], yv = vb[o];
        #pragma unroll
        for (int r = 0; r < 4; ++r) {
            yq += tq[r] * qA[o * RANK + r];
            yk += tk[r] * kA[o * RANK + r];
            yv += tv[r] * vA[o * RANK + r];
        }
        qrow[o] = yq; krow[o] = yk; vrowS[o] = yv;
    }
    __syncthreads();

    {
        const int c = t >> 5, i2 = t & 31;
        const float a  = qrow[c * 64 + i2], b2 = qrow[c * 64 + i2 + 32];
        const float ak = krow[c * 64 + i2], bk = krow[c * 64 + i2 + 32];
        float s  = a * a + b2 * b2;
        float sk = ak * ak + bk * bk;
        #pragma unroll
        for (int off = 16; off; off >>= 1) { s += __shfl_xor(s, off); sk += __shfl_xor(sk, off); }
        if (i2 == 0) { norms[c] = sqrtf(s); norms[8 + c] = sqrtf(sk); }
    }
    __syncthreads();

    #pragma unroll
    for (int h = 0; h < 2; ++h) {
        const int o = t + h * 256;
        const int c = o >> 6;
        qq_b[n * DIM + o] = f2bf(qrow[o] / (norms[c] + EPS));
        kq_b[n * DIM + o] = f2bf(krow[o] / (norms[8 + c] + EPS));
    }

    // vvT[d][n*8 + j] = vrowS[j*64 + d], one 16B store per d-row
    if (t < 64) {
        uint pk[4];
        #pragma unroll
        for (int i = 0; i < 4; ++i) {
            pk[i] = (uint)f2bf(vrowS[(2 * i) * 64 + t])
                  | ((uint)f2bf(vrowS[(2 * i + 1) * 64 + t]) << 16);
        }
        uint4 u4; u4.x = pk[0]; u4.y = pk[1]; u4.z = pk[2]; u4.w = pk[3];
        *(uint4*)((char*)vvT + (size_t)t * (NH * 2) + (size_t)n * 16) = u4;
    }
}

// ---------------------------------------------------------------------------
// Kernel 2: MFMA flash attention (no max tracking; logits in [-1/8, 1/8]).
// 256 blocks x 512 threads (8 waves). 64 queries/block, K-step = 128 keys.
// Wave w: S^T phase computes keys [w*16, w*16+16) x 64 q; PV phase computes
// d-tile (w&3) x q-half (w>>2). P^T round-trips through swizzled LDS.
// ---------------------------------------------------------------------------
__global__ __launch_bounds__(512) void attn_kernel(
    const ushort* __restrict__ qq_b, const ushort* __restrict__ kq_b,
    const ushort* __restrict__ vvT, float* __restrict__ att)
{
    __shared__ __align__(16) ushort Pb[64 * 128];   // [q][key] bf16, XOR-swizzled
    __shared__ float denp[8][64];
    __shared__ float denf[64];

    const int t = threadIdx.x;
    const int w = t >> 6, l = t & 63;
    const int qp = l & 15, g = l >> 4;
    const int qbase = blockIdx.x * 64;
    const int dtile = w & 3, qhalf = w >> 2;

    // Q fragments (B-operand): lane holds col q = qp, k-slice g*8 of dh
    bf16x8 Qf[4][2];
    #pragma unroll
    for (int qt = 0; qt < 4; ++qt)
        #pragma unroll
        for (int ks = 0; ks < 2; ++ks)
            Qf[qt][ks] = *(const bf16x8*)(qq_b + (size_t)(qbase + qt * 16 + qp) * DH + ks * 32 + g * 8);

    f32x4 num[2];
    #pragma unroll
    for (int j = 0; j < 2; ++j) { num[j][0] = 0.f; num[j][1] = 0.f; num[j][2] = 0.f; num[j][3] = 0.f; }
    float den[4] = {0.f, 0.f, 0.f, 0.f};

    for (int step = 0; step < NH / 128; ++step) {
        const int kb = step * 128;

        // ---- S^T = K . Q^T over this wave's 16 keys (A-frag: row = key) ----
        const int krow0 = kb + w * 16 + qp;
        const bf16x8 kf0 = *(const bf16x8*)(kq_b + (size_t)krow0 * DH + g * 8);
        const bf16x8 kf1 = *(const bf16x8*)(kq_b + (size_t)krow0 * DH + 32 + g * 8);

        #pragma unroll
        for (int qt = 0; qt < 4; ++qt) {
            f32x4 st; st[0] = 0.f; st[1] = 0.f; st[2] = 0.f; st[3] = 0.f;
            st = __builtin_amdgcn_mfma_f32_16x16x32_bf16(kf0, Qf[qt][0], st, 0, 0, 0);
            st = __builtin_amdgcn_mfma_f32_16x16x32_bf16(kf1, Qf[qt][1], st, 0, 0, 0);
            // exp(s/8) ~= 1 + s*(1/8 + s*(1/128 + s/3072)), |err| < 1.1e-5
            float wv[4];
            #pragma unroll
            for (int r = 0; r < 4; ++r) {
                const float s = st[r];
                wv[r] = 1.f + s * (0.125f + s * (0.0078125f + s * 3.25520833e-4f));
            }
            den[qt] += (wv[0] + wv[1]) + (wv[2] + wv[3]);
            const int q = qt * 16 + qp;
            uint2 pk;
            pk.x = (uint)f2bf(wv[0]) | ((uint)f2bf(wv[1]) << 16);
            pk.y = (uint)f2bf(wv[2]) | ((uint)f2bf(wv[3]) << 16);
            const uint byte = (uint)(q * 256 + (w * 16 + g * 4) * 2) ^ ((uint)(q & 7) << 4);
            *(uint2*)((char*)Pb + byte) = pk;
        }
        __syncthreads();

        // ---- numT[d][q] += V^T . P^T ----
        #pragma unroll
        for (int ks2 = 0; ks2 < 4; ++ks2) {
            const bf16x8 vf = *(const bf16x8*)(vvT + (size_t)(dtile * 16 + qp) * NH + kb + ks2 * 32 + g * 8);
            #pragma unroll
            for (int j = 0; j < 2; ++j) {
                const int q = (qhalf * 2 + j) * 16 + qp;
                const uint byte = (uint)(q * 256 + ks2 * 64 + g * 16) ^ ((uint)(q & 7) << 4);
                const bf16x8 pf = *(const bf16x8*)((const char*)Pb + byte);
                num[j] = __builtin_amdgcn_mfma_f32_16x16x32_bf16(vf, pf, num[j], 0, 0, 0);
            }
        }
        __syncthreads();
    }

    // ---- den reduction: lane partials -> per-q totals ----
    #pragma unroll
    for (int qt = 0; qt < 4; ++qt) {
        den[qt] += __shfl_xor(den[qt], 16);
        den[qt] += __shfl_xor(den[qt], 32);
    }
    if (g == 0) {
        #pragma unroll
        for (int qt = 0; qt < 4; ++qt) denp[w][qt * 16 + qp] = den[qt];
    }
    __syncthreads();
    if (t < 64) {
        float s = 0.f;
        #pragma unroll
        for (int i = 0; i < 8; ++i) s += denp[i][t];
        denf[t] = 1.f / s;
    }
    __syncthreads();

    // ---- epilogue: att[q][d] = numT[d][q] * (1/den[q]) ----
    #pragma unroll
    for (int j = 0; j < 2; ++j) {
        const int q = (qhalf * 2 + j) * 16 + qp;
        const float inv = denf[q];
        float4 o4;
        o4.x = num[j][0] * inv;
        o4.y = num[j][1] * inv;
        o4.z = num[j][2] * inv;
        o4.w = num[j][3] * inv;
        *(float4*)&att[(size_t)(qbase + q) * DH + dtile * 16 + g * 4] = o4;
    }
}

// ---------------------------------------------------------------------------
// Kernel 3: measure (per-head squared-amplitude normalize) + TT output proj.
// ---------------------------------------------------------------------------
__global__ __launch_bounds__(256) void out_proj(
    const float* __restrict__ att, const float* __restrict__ oA,
    const float* __restrict__ oB, const float* __restrict__ ob,
    float* __restrict__ out)
{
    __shared__ float csum[8];
    __shared__ float wred[4][4];
    __shared__ float tvals[4];

    const int n = blockIdx.x, t = threadIdx.x;
    const int wid = t >> 6, lane = t & 63;

    const float a0 = att[n * DIM + t];
    const float a1 = att[n * DIM + t + 256];
    float s0 = a0 * a0, s1 = a1 * a1;
    #pragma unroll
    for (int off = 32; off; off >>= 1) { s0 += __shfl_xor(s0, off); s1 += __shfl_xor(s1, off); }
    if (lane == 0) { csum[wid] = s0; csum[4 + wid] = s1; }
    __syncthreads();

    const float m0 = a0 * a0 / (csum[wid] + EPS);
    const float m1 = a1 * a1 / (csum[4 + wid] + EPS);

    float p[4];
    #pragma unroll
    for (int r = 0; r < 4; ++r) p[r] = m0 * oB[r * DIM + t] + m1 * oB[r * DIM + t + 256];
    #pragma unroll
    for (int r = 0; r < 4; ++r) {
        #pragma unroll
        for (int off = 32; off; off >>= 1) p[r] += __shfl_xor(p[r], off);
    }
    if (lane == 0) {
        #pragma unroll
        for (int r = 0; r < 4; ++r) wred[wid][r] = p[r];
    }
    __syncthreads();
    if (t < 4) tvals[t] = wred[0][t] + wred[1][t] + wred[2][t] + wred[3][t];
    __syncthreads();

    #pragma unroll
    for (int h = 0; h < 2; ++h) {
        const int o = t + h * 256;
        float y = ob[o];
        #pragma unroll
        for (int r = 0; r < 4; ++r) y += tvals[r] * oA[o * RANK + r];
        out[n * DIM + o] = y;
    }
}

// ---------------------------------------------------------------------------
extern "C" void kernel_launch(void* const* d_in, const int* in_sizes, int n_in,
                              void* d_out, int out_size, void* d_ws, size_t ws_size,
                              hipStream_t stream) {
    const float* x  = (const float*)d_in[0];
    const float* qA = (const float*)d_in[1];
    const float* qB = (const float*)d_in[2];
    const float* qb = (const float*)d_in[3];
    const float* kA = (const float*)d_in[4];
    const float* kB = (const float*)d_in[5];
    const float* kb = (const float*)d_in[6];
    const float* vA = (const float*)d_in[7];
    const float* vB = (const float*)d_in[8];
    const float* vb = (const float*)d_in[9];
    const float* oA = (const float*)d_in[10];
    const float* oB = (const float*)d_in[11];
    const float* ob = (const float*)d_in[12];

    ushort* qq_b = (ushort*)d_ws;                   // 2 MB
    ushort* kq_b = qq_b + (size_t)NH * DH;          // 2 MB
    ushort* vvT  = kq_b + (size_t)NH * DH;          // 2 MB  [DH][NH]
    float*  att  = (float*)(vvT + (size_t)NH * DH); // 4 MB
    float*  out  = (float*)d_out;

    proj_qkv<<<NROW, 256, 0, stream>>>(x, qA, qB, qb, kA, kB, kb, vA, vB, vb, qq_b, kq_b, vvT);
    attn_kernel<<<NH / 64, 512, 0, stream>>>(qq_b, kq_b, vvT, att);
    out_proj<<<NROW, 256, 0, stream>>>(att, oA, oB, ob, out);
}

// Round 3
// 124.555 us; speedup vs baseline: 28.7442x; 2.5339x over previous
//
#include <hip/hip_runtime.h>
#include <math.h>

#define DIM    512
#define RANK   4
#define NROW   2048   // BATCH * SEQ
#define DH     64
#define NH     16384  // NROW * HEADS
#define EPS    1e-8f
#define NCHUNK 4
#define KCHUNK 4096   // keys per block
#define KSTEP  64
#define NSTEP  (KCHUNK / KSTEP)     // 64
#define EPSDEN2 2.68435456f         // EPS * NH * NH  (den ~= NH; error < 1e-6 rel)

typedef short bf16x8 __attribute__((ext_vector_type(8)));
typedef float f32x4  __attribute__((ext_vector_type(4)));

static __device__ __forceinline__ ushort f2bf(float f) {
    uint u = __float_as_uint(f);
    u += 0x7FFFu + ((u >> 16) & 1u);   // round-to-nearest-even
    return (ushort)(u >> 16);
}
static __device__ __forceinline__ uint cvtpk_bf16(float a, float b) {
    uint r;
    asm("v_cvt_pk_bf16_f32 %0, %1, %2" : "=v"(r) : "v"(a), "v"(b));
    return r;
}
static __device__ __forceinline__ uint pkh2(float a, float b) {
    _Float16 ha = (_Float16)a, hb = (_Float16)b;
    return (uint)__builtin_bit_cast(ushort, ha) | ((uint)__builtin_bit_cast(ushort, hb) << 16);
}
static __device__ __forceinline__ float h2f(ushort u) {
    return (float)__builtin_bit_cast(_Float16, u);
}

// ---------------------------------------------------------------------------
// Kernel 1: TT projections q,k,v + L2-normalize q,k per head-row.
// Outputs: qq_b/kq_b bf16 [NH][DH], vvT bf16 [DH][NH].
// ---------------------------------------------------------------------------
__global__ __launch_bounds__(256) void proj_qkv(
    const float* __restrict__ x,
    const float* __restrict__ qA, const float* __restrict__ qB, const float* __restrict__ qb,
    const float* __restrict__ kA, const float* __restrict__ kB, const float* __restrict__ kb,
    const float* __restrict__ vA, const float* __restrict__ vB, const float* __restrict__ vb,
    ushort* __restrict__ qq_b, ushort* __restrict__ kq_b, ushort* __restrict__ vvT)
{
    __shared__ float qrow[DIM], krow[DIM], vrowS[DIM];
    __shared__ float wred[4][12];
    __shared__ float tvals[12];
    __shared__ float norms[16];

    const int n = blockIdx.x, t = threadIdx.x;
    const int wid = t >> 6, lane = t & 63;

    const float x0 = x[n * DIM + t];
    const float x1 = x[n * DIM + t + 256];

    float p[12];
    #pragma unroll
    for (int r = 0; r < 4; ++r) {
        p[r]     = x0 * qB[r * DIM + t] + x1 * qB[r * DIM + t + 256];
        p[4 + r] = x0 * kB[r * DIM + t] + x1 * kB[r * DIM + t + 256];
        p[8 + r] = x0 * vB[r * DIM + t] + x1 * vB[r * DIM + t + 256];
    }
    #pragma unroll
    for (int i = 0; i < 12; ++i) {
        #pragma unroll
        for (int off = 32; off; off >>= 1) p[i] += __shfl_xor(p[i], off);
    }
    if (lane == 0) {
        #pragma unroll
        for (int i = 0; i < 12; ++i) wred[wid][i] = p[i];
    }
    __syncthreads();
    if (t < 12) tvals[t] = wred[0][t] + wred[1][t] + wred[2][t] + wred[3][t];
    __syncthreads();

    float tq[4], tk[4], tv[4];
    #pragma unroll
    for (int r = 0; r < 4; ++r) { tq[r] = tvals[r]; tk[r] = tvals[4 + r]; tv[r] = tvals[8 + r]; }

    #pragma unroll
    for (int h = 0; h < 2; ++h) {
        const int o = t + h * 256;
        float yq = qb[o], yk = kb[o], yv = vb[o];
        #pragma unroll
        for (int r = 0; r < 4; ++r) {
            yq += tq[r] * qA[o * RANK + r];
            yk += tk[r] * kA[o * RANK + r];
            yv += tv[r] * vA[o * RANK + r];
        }
        qrow[o] = yq; krow[o] = yk; vrowS[o] = yv;
    }
    __syncthreads();

    {
        const int c = t >> 5, i2 = t & 31;
        const float a  = qrow[c * 64 + i2], b2 = qrow[c * 64 + i2 + 32];
        const float ak = krow[c * 64 + i2], bk = krow[c * 64 + i2 + 32];
        float s  = a * a + b2 * b2;
        float sk = ak * ak + bk * bk;
        #pragma unroll
        for (int off = 16; off; off >>= 1) { s += __shfl_xor(s, off); sk += __shfl_xor(sk, off); }
        if (i2 == 0) { norms[c] = sqrtf(s); norms[8 + c] = sqrtf(sk); }
    }
    __syncthreads();

    #pragma unroll
    for (int h = 0; h < 2; ++h) {
        const int o = t + h * 256;
        const int c = o >> 6;
        qq_b[n * DIM + o] = f2bf(qrow[o] / (norms[c] + EPS));
        kq_b[n * DIM + o] = f2bf(krow[o] / (norms[8 + c] + EPS));
    }

    // vvT[d][n*8 + j] = vrowS[j*64 + d]
    if (t < 64) {
        uint pk[4];
        #pragma unroll
        for (int i = 0; i < 4; ++i) {
            pk[i] = (uint)f2bf(vrowS[(2 * i) * 64 + t])
                  | ((uint)f2bf(vrowS[(2 * i + 1) * 64 + t]) << 16);
        }
        uint4 u4; u4.x = pk[0]; u4.y = pk[1]; u4.z = pk[2]; u4.w = pk[3];
        *(uint4*)((char*)vvT + (size_t)t * (NH * 2) + (size_t)n * 16) = u4;
    }
}

// ---------------------------------------------------------------------------
// Kernel 2: MFMA flash attention, no softmax max/den needed.
// Grid: 64 q-blocks (256 q) x 4 key-chunks. Block: 8 waves, wave owns 32 q.
// K/V tiles (64 keys) double-buffered in LDS (XOR-swizzled), staged
// global->reg->LDS with early-issued loads; ONE barrier per step.
// P stays in registers: cvt_pk to bf16 + ds_bpermute redistribution.
// Writes fp16 partial numerators [chunk][q][d].
// ---------------------------------------------------------------------------
__global__ __launch_bounds__(512) void attn_kernel(
    const ushort* __restrict__ qq_b, const ushort* __restrict__ kq_b,
    const ushort* __restrict__ vvT, ushort* __restrict__ numpart)
{
    __shared__ __align__(16) char smem[2][16384];   // [buf][ K 8KB | V 8KB ]

    const int t = threadIdx.x;
    const int w = t >> 6, l = t & 63;
    const int qp = l & 15, g = l >> 4;
    const int qbase = (blockIdx.x >> 2) * 256;
    const int chunk = blockIdx.x & 3;
    const int kbase = chunk * KCHUNK;

    // staging geometry: thread t covers (row = t>>3, 16B slot = t&7)
    const int srow = t >> 3;
    const int sslot = t & 7;
    const int wslot = sslot ^ (srow & 7);                     // write-side swizzle
    const int ldst_off = srow * 128 + wslot * 16;
    const size_t kgbyte0 = ((size_t)(kbase + srow)) * 128 + (size_t)sslot * 16;
    const size_t vgbyte0 = (size_t)srow * (NH * 2) + (size_t)kbase * 2 + (size_t)sslot * 16;

    // Q fragments (B-operand): lane (qp,g): col q, dh = ks*32 + g*8 .. +8
    bf16x8 Qf[2][2];
    #pragma unroll
    for (int qt = 0; qt < 2; ++qt)
        #pragma unroll
        for (int ks = 0; ks < 2; ++ks)
            Qf[qt][ks] = *(const bf16x8*)(qq_b + (size_t)(qbase + w * 32 + qt * 16 + qp) * DH + ks * 32 + g * 8);

    f32x4 acc[2][4];
    #pragma unroll
    for (int qt = 0; qt < 2; ++qt)
        #pragma unroll
        for (int dt = 0; dt < 4; ++dt) { acc[qt][dt][0] = 0.f; acc[qt][dt][1] = 0.f; acc[qt][dt][2] = 0.f; acc[qt][dt][3] = 0.f; }

    // bpermute source-lane byte addrs (constant per lane)
    const int srcA = (qp + ((g & 1) << 5)) << 2;   // lane qp + 32*(g&1)
    const int srcB = srcA + 64;                    // +16 lanes
    const bool hiT = (g & 2) != 0;

    const int swz = qp & 7;

    // prologue: stage step 0, issue loads for step 1
    uint4 kreg = *(const uint4*)((const char*)kq_b + kgbyte0);
    uint4 vreg = *(const uint4*)((const char*)vvT + vgbyte0);
    *(uint4*)(smem[0] + ldst_off) = kreg;
    *(uint4*)(smem[0] + 8192 + ldst_off) = vreg;
    kreg = *(const uint4*)((const char*)kq_b + kgbyte0 + 8192);
    vreg = *(const uint4*)((const char*)vvT + vgbyte0 + 128);
    __syncthreads();

    for (int s = 0; s < NSTEP; ++s) {
        const int cur = s & 1;
        // write staged regs (data for step s+1) into the other buffer
        if (s + 1 < NSTEP) {
            char* db = smem[cur ^ 1];
            *(uint4*)(db + ldst_off) = kreg;
            *(uint4*)(db + 8192 + ldst_off) = vreg;
        }
        // early-issue loads for step s+2 (hide HBM/L2 latency under compute)
        if (s + 2 < NSTEP) {
            kreg = *(const uint4*)((const char*)kq_b + kgbyte0 + (size_t)(s + 2) * 8192);
            vreg = *(const uint4*)((const char*)vvT + vgbyte0 + (size_t)(s + 2) * 128);
        }

        const char* Kb = smem[cur];
        const char* Vb = smem[cur] + 8192;

        // --- K fragments from LDS (swizzled) ---
        bf16x8 kf[4][2];
        #pragma unroll
        for (int kt = 0; kt < 4; ++kt)
            #pragma unroll
            for (int ks = 0; ks < 2; ++ks)
                kf[kt][ks] = *(const bf16x8*)(Kb + (kt * 16 + qp) * 128 + ((((ks << 2) | g) ^ swz) << 4));

        // --- S^T + exp + pack: u[kt][qt][2] ---
        uint u[4][2][2];
        #pragma unroll
        for (int qt = 0; qt < 2; ++qt) {
            #pragma unroll
            for (int kt = 0; kt < 4; ++kt) {
                f32x4 st; st[0] = 0.f; st[1] = 0.f; st[2] = 0.f; st[3] = 0.f;
                st = __builtin_amdgcn_mfma_f32_16x16x32_bf16(kf[kt][0], Qf[qt][0], st, 0, 0, 0);
                st = __builtin_amdgcn_mfma_f32_16x16x32_bf16(kf[kt][1], Qf[qt][1], st, 0, 0, 0);
                const float w0 = __expf(st[0] * 0.125f);
                const float w1 = __expf(st[1] * 0.125f);
                const float w2 = __expf(st[2] * 0.125f);
                const float w3 = __expf(st[3] * 0.125f);
                u[kt][qt][0] = cvtpk_bf16(w0, w1);
                u[kt][qt][1] = cvtpk_bf16(w2, w3);
            }
        }

        // --- PV: gather P B-frags via bpermute, V A-frags from LDS ---
        #pragma unroll
        for (int kg = 0; kg < 2; ++kg) {
            bf16x8 pf[2];
            #pragma unroll
            for (int qt = 0; qt < 2; ++qt) {
                const int kt0 = kg * 2, kt1 = kg * 2 + 1;
                int a0 = __builtin_amdgcn_ds_bpermute(srcA, (int)u[kt0][qt][0]);
                int a1 = __builtin_amdgcn_ds_bpermute(srcA, (int)u[kt1][qt][0]);
                int b0 = __builtin_amdgcn_ds_bpermute(srcA, (int)u[kt0][qt][1]);
                int b1 = __builtin_amdgcn_ds_bpermute(srcA, (int)u[kt1][qt][1]);
                int c0 = __builtin_amdgcn_ds_bpermute(srcB, (int)u[kt0][qt][0]);
                int c1 = __builtin_amdgcn_ds_bpermute(srcB, (int)u[kt1][qt][0]);
                int d0 = __builtin_amdgcn_ds_bpermute(srcB, (int)u[kt0][qt][1]);
                int d1 = __builtin_amdgcn_ds_bpermute(srcB, (int)u[kt1][qt][1]);
                union { int i[4]; bf16x8 v; } pu;
                pu.i[0] = hiT ? a1 : a0;
                pu.i[1] = hiT ? b1 : b0;
                pu.i[2] = hiT ? c1 : c0;
                pu.i[3] = hiT ? d1 : d0;
                pf[qt] = pu.v;
            }
            #pragma unroll
            for (int dt = 0; dt < 4; ++dt) {
                const bf16x8 vf = *(const bf16x8*)(Vb + (dt * 16 + qp) * 128 + ((((kg << 2) | g) ^ swz) << 4));
                #pragma unroll
                for (int qt = 0; qt < 2; ++qt)
                    acc[qt][dt] = __builtin_amdgcn_mfma_f32_16x16x32_bf16(vf, pf[qt], acc[qt][dt], 0, 0, 0);
            }
        }
        __syncthreads();
    }

    // epilogue: fp16 partial numerators. lane (qp,g): num[d=dt*16+4g+r][q=..+qt*16+qp]
    #pragma unroll
    for (int qt = 0; qt < 2; ++qt) {
        const int q = qbase + w * 32 + qt * 16 + qp;
        #pragma unroll
        for (int dt = 0; dt < 4; ++dt) {
            uint2 st8;
            st8.x = pkh2(acc[qt][dt][0], acc[qt][dt][1]);
            st8.y = pkh2(acc[qt][dt][2], acc[qt][dt][3]);
            *(uint2*)(numpart + (((size_t)chunk << 20) + (size_t)q * 64 + dt * 16 + g * 4)) = st8;
        }
    }
}

// ---------------------------------------------------------------------------
// Kernel 3: finalize = chunk-reduce + measure (den-free) + TT output proj.
// measure = num^2 / (sum_d num^2 + EPS*NH^2)   [softmax den cancels exactly]
// ---------------------------------------------------------------------------
__global__ __launch_bounds__(256) void finalize(
    const ushort* __restrict__ numpart, const float* __restrict__ oA,
    const float* __restrict__ oB, const float* __restrict__ ob,
    float* __restrict__ out)
{
    __shared__ float csum[8];
    __shared__ float wred[4][4];
    __shared__ float tvals[4];

    const int n = blockIdx.x, t = threadIdx.x;
    const int wid = t >> 6, lane = t & 63;

    const size_t b0 = (size_t)(n * 8 + wid) * 64 + (t & 63);
    const size_t b1 = (size_t)(n * 8 + 4 + wid) * 64 + (t & 63);
    float a0 = 0.f, a1 = 0.f;
    #pragma unroll
    for (int c = 0; c < NCHUNK; ++c) {
        a0 += h2f(numpart[((size_t)c << 20) + b0]);
        a1 += h2f(numpart[((size_t)c << 20) + b1]);
    }

    float s0 = a0 * a0, s1 = a1 * a1;
    #pragma unroll
    for (int off = 32; off; off >>= 1) { s0 += __shfl_xor(s0, off); s1 += __shfl_xor(s1, off); }
    if (lane == 0) { csum[wid] = s0; csum[4 + wid] = s1; }
    __syncthreads();

    const float m0 = a0 * a0 / (csum[wid] + EPSDEN2);
    const float m1 = a1 * a1 / (csum[4 + wid] + EPSDEN2);

    float p[4];
    #pragma unroll
    for (int r = 0; r < 4; ++r) p[r] = m0 * oB[r * DIM + t] + m1 * oB[r * DIM + t + 256];
    #pragma unroll
    for (int r = 0; r < 4; ++r) {
        #pragma unroll
        for (int off = 32; off; off >>= 1) p[r] += __shfl_xor(p[r], off);
    }
    if (lane == 0) {
        #pragma unroll
        for (int r = 0; r < 4; ++r) wred[wid][r] = p[r];
    }
    __syncthreads();
    if (t < 4) tvals[t] = wred[0][t] + wred[1][t] + wred[2][t] + wred[3][t];
    __syncthreads();

    #pragma unroll
    for (int h = 0; h < 2; ++h) {
        const int o = t + h * 256;
        float y = ob[o];
        #pragma unroll
        for (int r = 0; r < 4; ++r) y += tvals[r] * oA[o * RANK + r];
        out[n * DIM + o] = y;
    }
}

// ---------------------------------------------------------------------------
extern "C" void kernel_launch(void* const* d_in, const int* in_sizes, int n_in,
                              void* d_out, int out_size, void* d_ws, size_t ws_size,
                              hipStream_t stream) {
    const float* x  = (const float*)d_in[0];
    const float* qA = (const float*)d_in[1];
    const float* qB = (const float*)d_in[2];
    const float* qb = (const float*)d_in[3];
    const float* kA = (const float*)d_in[4];
    const float* kB = (const float*)d_in[5];
    const float* kb = (const float*)d_in[6];
    const float* vA = (const float*)d_in[7];
    const float* vB = (const float*)d_in[8];
    const float* vb = (const float*)d_in[9];
    const float* oA = (const float*)d_in[10];
    const float* oB = (const float*)d_in[11];
    const float* ob = (const float*)d_in[12];

    ushort* qq_b    = (ushort*)d_ws;                 // 2 MB bf16 [NH][64]
    ushort* kq_b    = qq_b + (size_t)NH * DH;        // 2 MB bf16 [NH][64]
    ushort* vvT     = kq_b + (size_t)NH * DH;        // 2 MB bf16 [64][NH]
    ushort* numpart = vvT + (size_t)NH * DH;         // 8 MB fp16 [4][NH][64]
    float*  out     = (float*)d_out;

    proj_qkv<<<NROW, 256, 0, stream>>>(x, qA, qB, qb, kA, kB, kb, vA, vB, vb, qq_b, kq_b, vvT);
    attn_kernel<<<256, 512, 0, stream>>>(qq_b, kq_b, vvT, numpart);
    finalize<<<NROW, 256, 0, stream>>>(numpart, oA, oB, ob, out);
}

// Round 4
// 110.022 us; speedup vs baseline: 32.5411x; 1.1321x over previous
//
#include <hip/hip_runtime.h>
#include <math.h>

#define DIM    512
#define RANK   4
#define NROW   2048   // BATCH * SEQ
#define DH     64
#define NH     16384  // NROW * HEADS
#define EPS    1e-8f
#define NCHUNK 4
#define KCHUNK 4096   // keys per block
#define NSTEP  (KCHUNK / 64)        // 64 steps of 64 keys
#define EPSDEN2 2.68435456f         // EPS * NH * NH  (den ~= NH; rel err < 2e-4 on a 1e-5-weight term)

typedef short  bf16x8 __attribute__((ext_vector_type(8)));
typedef ushort u16x8  __attribute__((ext_vector_type(8)));
typedef float  f32x16 __attribute__((ext_vector_type(16)));

static __device__ __forceinline__ ushort f2bf(float f) {
    uint u = __float_as_uint(f);
    u += 0x7FFFu + ((u >> 16) & 1u);   // round-to-nearest-even
    return (ushort)(u >> 16);
}
static __device__ __forceinline__ float bf2f(ushort u) {
    return __uint_as_float((uint)u << 16);
}
static __device__ __forceinline__ uint cvtpk_bf16(float a, float b) {
    uint r;
    asm("v_cvt_pk_bf16_f32 %0, %1, %2" : "=v"(r) : "v"(a), "v"(b));
    return r;
}
static __device__ __forceinline__ void pl32swap(uint& a, uint& b) {
    // swaps a's upper-32-lane values with b's lower-32-lane values
    asm("v_permlane32_swap_b32 %0, %1" : "+v"(a), "+v"(b));
}
// expm1(s/8), |s| <= ~1.01: 4th-order poly, abs err < 3e-7
static __device__ __forceinline__ float expm1_8(float s) {
    float t = fmaf(s, 1.01725260e-5f, 3.25520833e-4f);
    t = fmaf(s, t, 0.0078125f);
    t = fmaf(s, t, 0.125f);
    return s * t;
}

// ---------------------------------------------------------------------------
// Kernel 1: TT projections q,k,v + L2-normalize q,k per head-row.
// Outputs: qq_b/kq_b bf16 [NH][DH], vvT bf16 [DH][NH].
// ---------------------------------------------------------------------------
__global__ __launch_bounds__(256) void proj_qkv(
    const float* __restrict__ x,
    const float* __restrict__ qA, const float* __restrict__ qB, const float* __restrict__ qb,
    const float* __restrict__ kA, const float* __restrict__ kB, const float* __restrict__ kb,
    const float* __restrict__ vA, const float* __restrict__ vB, const float* __restrict__ vb,
    ushort* __restrict__ qq_b, ushort* __restrict__ kq_b, ushort* __restrict__ vvT)
{
    __shared__ float qrow[DIM], krow[DIM], vrowS[DIM];
    __shared__ float wred[4][12];
    __shared__ float tvals[12];
    __shared__ float norms[16];

    const int n = blockIdx.x, t = threadIdx.x;
    const int wid = t >> 6, lane = t & 63;

    const float x0 = x[n * DIM + t];
    const float x1 = x[n * DIM + t + 256];

    float p[12];
    #pragma unroll
    for (int r = 0; r < 4; ++r) {
        p[r]     = x0 * qB[r * DIM + t] + x1 * qB[r * DIM + t + 256];
        p[4 + r] = x0 * kB[r * DIM + t] + x1 * kB[r * DIM + t + 256];
        p[8 + r] = x0 * vB[r * DIM + t] + x1 * vB[r * DIM + t + 256];
    }
    #pragma unroll
    for (int i = 0; i < 12; ++i) {
        #pragma unroll
        for (int off = 32; off; off >>= 1) p[i] += __shfl_xor(p[i], off);
    }
    if (lane == 0) {
        #pragma unroll
        for (int i = 0; i < 12; ++i) wred[wid][i] = p[i];
    }
    __syncthreads();
    if (t < 12) tvals[t] = wred[0][t] + wred[1][t] + wred[2][t] + wred[3][t];
    __syncthreads();

    float tq[4], tk[4], tv[4];
    #pragma unroll
    for (int r = 0; r < 4; ++r) { tq[r] = tvals[r]; tk[r] = tvals[4 + r]; tv[r] = tvals[8 + r]; }

    #pragma unroll
    for (int h = 0; h < 2; ++h) {
        const int o = t + h * 256;
        float yq = qb[o], yk = kb[o], yv = vb[o];
        #pragma unroll
        for (int r = 0; r < 4; ++r) {
            yq += tq[r] * qA[o * RANK + r];
            yk += tk[r] * kA[o * RANK + r];
            yv += tv[r] * vA[o * RANK + r];
        }
        qrow[o] = yq; krow[o] = yk; vrowS[o] = yv;
    }
    __syncthreads();

    {
        const int c = t >> 5, i2 = t & 31;
        const float a  = qrow[c * 64 + i2], b2 = qrow[c * 64 + i2 + 32];
        const float ak = krow[c * 64 + i2], bk = krow[c * 64 + i2 + 32];
        float s  = a * a + b2 * b2;
        float sk = ak * ak + bk * bk;
        #pragma unroll
        for (int off = 16; off; off >>= 1) { s += __shfl_xor(s, off); sk += __shfl_xor(sk, off); }
        if (i2 == 0) { norms[c] = sqrtf(s); norms[8 + c] = sqrtf(sk); }
    }
    __syncthreads();

    #pragma unroll
    for (int h = 0; h < 2; ++h) {
        const int o = t + h * 256;
        const int c = o >> 6;
        qq_b[n * DIM + o] = f2bf(qrow[o] / (norms[c] + EPS));
        kq_b[n * DIM + o] = f2bf(krow[o] / (norms[8 + c] + EPS));
    }

    // vvT[d][n*8 + j] = vrowS[j*64 + d]
    if (t < 64) {
        uint pk[4];
        #pragma unroll
        for (int i = 0; i < 4; ++i) {
            pk[i] = (uint)f2bf(vrowS[(2 * i) * 64 + t])
                  | ((uint)f2bf(vrowS[(2 * i + 1) * 64 + t]) << 16);
        }
        uint4 u4; u4.x = pk[0]; u4.y = pk[1]; u4.z = pk[2]; u4.w = pk[3];
        *(uint4*)((char*)vvT + (size_t)t * (NH * 2) + (size_t)n * 16) = u4;
    }
}

// ---------------------------------------------------------------------------
// Kernel 1b: Vsum[d] = sum over all NH keys of v[key][d] (from bf16 vvT, fp32 acc)
// ---------------------------------------------------------------------------
__global__ __launch_bounds__(256) void vsum_kernel(
    const ushort* __restrict__ vvT, float* __restrict__ Vsum)
{
    __shared__ float red[4];
    const int d = blockIdx.x, t = threadIdx.x;
    const int wid = t >> 6, lane = t & 63;
    float s = 0.f;
    #pragma unroll
    for (int j = 0; j < 8; ++j) {
        const u16x8 u = *(const u16x8*)(vvT + (size_t)d * NH + (size_t)(j * 256 + t) * 8);
        #pragma unroll
        for (int e = 0; e < 8; ++e) s += bf2f(u[e]);
    }
    #pragma unroll
    for (int off = 32; off; off >>= 1) s += __shfl_xor(s, off);
    if (lane == 0) red[wid] = s;
    __syncthreads();
    if (t == 0) Vsum[d] = red[0] + red[1] + red[2] + red[3];
}

// ---------------------------------------------------------------------------
// Kernel 2: MFMA flash attention with P = expm1(s/8) (the +1 term is the
// query-independent Vsum, added in finalize). 32x32x16 MFMA; swapped QK^T so
// each lane owns its q's key-row; P redistributed in-register via
// v_permlane32_swap (no LDS). Grid: 64 q-blocks (256 q) x 4 key-chunks.
// Block: 8 waves; wave owns a 32-q strip. K/V double-buffered in LDS
// (XOR-swizzled), staged global->reg->LDS, ONE barrier per 64-key step.
// Writes bf16 partial numerators numpart[chunk][d][q].
// ---------------------------------------------------------------------------
__global__ __launch_bounds__(512) void attn_kernel(
    const ushort* __restrict__ qq_b, const ushort* __restrict__ kq_b,
    const ushort* __restrict__ vvT, ushort* __restrict__ numpart)
{
    __shared__ __align__(16) char smem[2][16384];   // [buf][ K 8KB | V 8KB ]

    const int t = threadIdx.x;
    const int w = t >> 6, l = t & 63;
    const int l31 = l & 31, hi = l >> 5;
    const int q0 = (blockIdx.x >> 2) * 256 + w * 32;
    const int chunk = blockIdx.x & 3;
    const int kbase = chunk * KCHUNK;

    // staging geometry: thread t stages (row = t>>3, 16B slot = t&7), swizzled
    const int srow = t >> 3, sslot = t & 7;
    const int woff = srow * 128 + ((sslot ^ (srow & 7)) << 4);
    const size_t kg0 = (size_t)(kbase + srow) * 128 + (sslot << 4);
    const size_t vg0 = (size_t)srow * (NH * 2) + (size_t)kbase * 2 + (sslot << 4);

    // Q fragments (B-operand of 32x32x16): lane: col q = q0+l31, k = w16*16+hi*8..+8
    bf16x8 Qf[4];
    #pragma unroll
    for (int w16 = 0; w16 < 4; ++w16)
        Qf[w16] = *(const bf16x8*)((const char*)qq_b + (size_t)(q0 + l31) * 128 + w16 * 32 + hi * 16);

    f32x16 acc[2];
    #pragma unroll
    for (int dt = 0; dt < 2; ++dt)
        #pragma unroll
        for (int r = 0; r < 16; ++r) acc[dt][r] = 0.f;

    // step-invariant swizzled LDS read offsets (kt*32 and dt*32 are 0 mod 8)
    int koff[2][4], voff[2][4];
    #pragma unroll
    for (int kt = 0; kt < 2; ++kt)
        #pragma unroll
        for (int w16 = 0; w16 < 4; ++w16)
            koff[kt][w16] = (kt * 32 + l31) * 128 + ((((w16 << 1) | hi) ^ (l31 & 7)) << 4);
    #pragma unroll
    for (int dt = 0; dt < 2; ++dt)
        #pragma unroll
        for (int kw = 0; kw < 4; ++kw)
            voff[dt][kw] = (dt * 32 + l31) * 128 + ((((kw << 1) | hi) ^ (l31 & 7)) << 4);

    // prologue: stage step 0, issue loads for step 1
    uint4 kreg = *(const uint4*)((const char*)kq_b + kg0);
    uint4 vreg = *(const uint4*)((const char*)vvT + vg0);
    *(uint4*)(smem[0] + woff) = kreg;
    *(uint4*)(smem[0] + 8192 + woff) = vreg;
    kreg = *(const uint4*)((const char*)kq_b + kg0 + 8192);
    vreg = *(const uint4*)((const char*)vvT + vg0 + 128);
    __syncthreads();

    for (int s = 0; s < NSTEP; ++s) {
        const int cur = s & 1;
        if (s + 1 < NSTEP) {                      // write step s+1's data
            char* db = smem[cur ^ 1];
            *(uint4*)(db + woff) = kreg;
            *(uint4*)(db + 8192 + woff) = vreg;
        }
        if (s + 2 < NSTEP) {                      // early-issue step s+2's loads
            kreg = *(const uint4*)((const char*)kq_b + kg0 + (size_t)(s + 2) * 8192);
            vreg = *(const uint4*)((const char*)vvT + vg0 + (size_t)(s + 2) * 128);
        }
        const char* Kb = smem[cur];
        const char* Vb = smem[cur] + 8192;

        #pragma unroll
        for (int kt = 0; kt < 2; ++kt) {
            // K A-frags: lane: key-row kt*32+l31, dh = w16*16+hi*8..+8
            bf16x8 kf[4];
            #pragma unroll
            for (int w16 = 0; w16 < 4; ++w16)
                kf[w16] = *(const bf16x8*)(Kb + koff[kt][w16]);

            // S^T tile: D[key][q], col q = l31, row key = (r&3)+8*(r>>2)+4*hi
            f32x16 st;
            #pragma unroll
            for (int r = 0; r < 16; ++r) st[r] = 0.f;
            __builtin_amdgcn_s_setprio(1);
            #pragma unroll
            for (int w16 = 0; w16 < 4; ++w16)
                st = __builtin_amdgcn_mfma_f32_32x32x16_bf16(kf[w16], Qf[w16], st, 0, 0, 0);
            __builtin_amdgcn_s_setprio(0);

            // P = expm1(s/8) -> bf16 pairs; permlane32_swap redistributes so
            // lane l31 holds its q's keys: lo lanes keys 0..15, hi keys +8 shift
            uint pk[8];
            #pragma unroll
            for (int j = 0; j < 8; ++j)
                pk[j] = cvtpk_bf16(expm1_8(st[2 * j]), expm1_8(st[2 * j + 1]));
            pl32swap(pk[0], pk[2]); pl32swap(pk[1], pk[3]);
            pl32swap(pk[4], pk[6]); pl32swap(pk[5], pk[7]);
            // now pa(kw=0) = {pk0,pk1,pk2,pk3}: lo keys 0..7 / hi keys 8..15
            //     pa(kw=1) = {pk4,pk5,pk6,pk7}: lo keys 16..23 / hi keys 24..31

            __builtin_amdgcn_s_setprio(1);
            #pragma unroll
            for (int kw = 0; kw < 2; ++kw) {
                union { uint u[4]; bf16x8 v; } pa;
                pa.u[0] = pk[kw * 4]; pa.u[1] = pk[kw * 4 + 1];
                pa.u[2] = pk[kw * 4 + 2]; pa.u[3] = pk[kw * 4 + 3];
                #pragma unroll
                for (int dt = 0; dt < 2; ++dt) {
                    const bf16x8 vf = *(const bf16x8*)(Vb + voff[dt][kt * 2 + kw]);
                    acc[dt] = __builtin_amdgcn_mfma_f32_32x32x16_bf16(pa.v, vf, acc[dt], 0, 0, 0);
                }
            }
            __builtin_amdgcn_s_setprio(0);
        }
        __syncthreads();
    }

    // epilogue: acc D[q][d]: col d = dt*32+l31, q-rows in runs of 4:
    // regs 4g..4g+3 -> q = q0 + 8g + 4hi + 0..3. Store bf16 [chunk][d][q].
    #pragma unroll
    for (int dt = 0; dt < 2; ++dt) {
        const int d = dt * 32 + l31;
        #pragma unroll
        for (int g = 0; g < 4; ++g) {
            uint2 u2;
            u2.x = cvtpk_bf16(acc[dt][4 * g],     acc[dt][4 * g + 1]);
            u2.y = cvtpk_bf16(acc[dt][4 * g + 2], acc[dt][4 * g + 3]);
            const int qr = q0 + 8 * g + 4 * hi;
            *(uint2*)(numpart + (((size_t)(chunk * 64 + d)) << 14) + qr) = u2;
        }
    }
}

// ---------------------------------------------------------------------------
// Kernel 3: finalize = Vsum + chunk-reduce + measure (den-free) + TT out proj.
// measure = num^2 / (sum_d num^2 + EPS*NH^2)   [softmax den cancels exactly]
// ---------------------------------------------------------------------------
__global__ __launch_bounds__(256) void finalize(
    const ushort* __restrict__ numpart, const float* __restrict__ Vsum,
    const float* __restrict__ oA, const float* __restrict__ oB,
    const float* __restrict__ ob, float* __restrict__ out)
{
    __shared__ float L[8][4][64];
    __shared__ float csum[8];
    __shared__ float wred[4][4];
    __shared__ float tvals[4];

    const int n = blockIdx.x, t = threadIdx.x;
    const int wid = t >> 6, lane = t & 63;

    {   // thread t loads the 8-query run for (chunk = t>>6, d = t&63)
        const int cc = t >> 6, dd = t & 63;
        const uint4 u = *(const uint4*)(numpart + (((size_t)(cc * 64 + dd)) << 14) + n * 8);
        L[0][cc][dd] = bf2f((ushort)(u.x & 0xffff));
        L[1][cc][dd] = bf2f((ushort)(u.x >> 16));
        L[2][cc][dd] = bf2f((ushort)(u.y & 0xffff));
        L[3][cc][dd] = bf2f((ushort)(u.y >> 16));
        L[4][cc][dd] = bf2f((ushort)(u.z & 0xffff));
        L[5][cc][dd] = bf2f((ushort)(u.z >> 16));
        L[6][cc][dd] = bf2f((ushort)(u.w & 0xffff));
        L[7][cc][dd] = bf2f((ushort)(u.w >> 16));
    }
    __syncthreads();

    const float vs = Vsum[lane];
    const float a0 = vs + L[wid][0][lane]     + L[wid][1][lane]     + L[wid][2][lane]     + L[wid][3][lane];
    const float a1 = vs + L[wid + 4][0][lane] + L[wid + 4][1][lane] + L[wid + 4][2][lane] + L[wid + 4][3][lane];

    float s0 = a0 * a0, s1 = a1 * a1;
    #pragma unroll
    for (int off = 32; off; off >>= 1) { s0 += __shfl_xor(s0, off); s1 += __shfl_xor(s1, off); }
    if (lane == 0) { csum[wid] = s0; csum[4 + wid] = s1; }
    __syncthreads();

    const float m0 = a0 * a0 / (csum[wid] + EPSDEN2);
    const float m1 = a1 * a1 / (csum[4 + wid] + EPSDEN2);

    float p[4];
    #pragma unroll
    for (int r = 0; r < 4; ++r) p[r] = m0 * oB[r * DIM + t] + m1 * oB[r * DIM + t + 256];
    #pragma unroll
    for (int r = 0; r < 4; ++r) {
        #pragma unroll
        for (int off = 32; off; off >>= 1) p[r] += __shfl_xor(p[r], off);
    }
    if (lane == 0) {
        #pragma unroll
        for (int r = 0; r < 4; ++r) wred[wid][r] = p[r];
    }
    __syncthreads();
    if (t < 4) tvals[t] = wred[0][t] + wred[1][t] + wred[2][t] + wred[3][t];
    __syncthreads();

    #pragma unroll
    for (int h = 0; h < 2; ++h) {
        const int o = t + h * 256;
        float y = ob[o];
        #pragma unroll
        for (int r = 0; r < 4; ++r) y += tvals[r] * oA[o * RANK + r];
        out[n * DIM + o] = y;
    }
}

// ---------------------------------------------------------------------------
extern "C" void kernel_launch(void* const* d_in, const int* in_sizes, int n_in,
                              void* d_out, int out_size, void* d_ws, size_t ws_size,
                              hipStream_t stream) {
    const float* x  = (const float*)d_in[0];
    const float* qA = (const float*)d_in[1];
    const float* qB = (const float*)d_in[2];
    const float* qb = (const float*)d_in[3];
    const float* kA = (const float*)d_in[4];
    const float* kB = (const float*)d_in[5];
    const float* kb = (const float*)d_in[6];
    const float* vA = (const float*)d_in[7];
    const float* vB = (const float*)d_in[8];
    const float* vb = (const float*)d_in[9];
    const float* oA = (const float*)d_in[10];
    const float* oB = (const float*)d_in[11];
    const float* ob = (const float*)d_in[12];

    ushort* qq_b    = (ushort*)d_ws;                      // 2 MB bf16 [NH][64]
    ushort* kq_b    = qq_b + (size_t)NH * DH;             // 2 MB bf16 [NH][64]
    ushort* vvT     = kq_b + (size_t)NH * DH;             // 2 MB bf16 [64][NH]
    ushort* numpart = vvT + (size_t)NH * DH;              // 8 MB bf16 [4][64][NH]
    float*  Vsum    = (float*)(numpart + (size_t)NCHUNK * DH * NH);  // 256 B
    float*  out     = (float*)d_out;

    proj_qkv<<<NROW, 256, 0, stream>>>(x, qA, qB, qb, kA, kB, kb, vA, vB, vb, qq_b, kq_b, vvT);
    vsum_kernel<<<DH, 256, 0, stream>>>(vvT, Vsum);
    attn_kernel<<<256, 512, 0, stream>>>(qq_b, kq_b, vvT, numpart);
    finalize<<<NROW, 256, 0, stream>>>(numpart, Vsum, oA, oB, ob, out);
}